// Round 14
// baseline (199.592 us; speedup 1.0000x reference)
//
#include <hip/hip_runtime.h>
#include <hip/hip_bf16.h>
#include <math.h>

// Problem: B=32, N=128, S=64, D=512
// Output: [B,N] f32, each row sorted descending.
// Round 14 (base r13=181.9us): algebraic collapse. k_wprep (standalone 128
// blocks, launched first) computes Mk=Wk^T@Wq and Wpv=Wp@Wv in f32; then
// qk = Mk@(fusion+cond) (1 bmv, replaces bmv(q)+k_qk) and
// ne = Wpv@vsum + bp  (1 bmv, replaces bmv(Wv)+bmv(Wp); r12-proven path).
// 9 launches. No device-side sync (r4/r5/r11: barriers lose to launch gaps);
// no co-compiled heavy paths in k2 (r12: VGPR occupancy cliff).

#define BB 32
#define NN 128
#define SS 64
#define DD 512

typedef __attribute__((ext_vector_type(8))) short short8;
typedef __attribute__((ext_vector_type(4))) float f32x4;

__device__ __forceinline__ ushort f2bf(float f) {
    unsigned u = __float_as_uint(f);
    unsigned r = (u + 0x7fffu + ((u >> 16) & 1u)) >> 16;
    return (ushort)r;
}
__device__ __forceinline__ float bf2f(ushort u) {
    return __uint_as_float(((unsigned)u) << 16);
}

// Batched wave-dot: 4 rows of W (stride ldw) dotted with x (in regs xa/xb).
__device__ __forceinline__ void wave_dot512x4(
    const float* __restrict__ w, size_t ldw, float4 xa, float4 xb,
    int lane, float out[4]) {
    float4 ra[4], rb[4];
#pragma unroll
    for (int r = 0; r < 4; ++r) {
        const float4* row = reinterpret_cast<const float4*>(w + (size_t)r * ldw);
        ra[r] = row[lane * 2];
        rb[r] = row[lane * 2 + 1];
    }
#pragma unroll
    for (int r = 0; r < 4; ++r) {
        float s = ra[r].x * xa.x + ra[r].y * xa.y + ra[r].z * xa.z + ra[r].w * xa.w
                + rb[r].x * xb.x + rb[r].y * xb.y + rb[r].z * xb.z + rb[r].w * xb.w;
#pragma unroll
        for (int off = 32; off; off >>= 1) s += __shfl_xor(s, off);
        out[r] = s;
    }
}

// k_wprep: 128 blocks. g<64: Wpv[i][d] = sum_j Wp[i][j]*Wv[j][d]  (r12 tile)
//          g>=64: Mk[c][i] = sum_j Wk[j][c]*Wq[j][i]
// 64x64 f32 tiles, K-chunks of 32 staged in LDS, 4x4 acc per thread.
__global__ __launch_bounds__(256) void k_wprep(
    const float* __restrict__ Wp, const float* __restrict__ Wv,
    const float* __restrict__ Wk, const float* __restrict__ Wq,
    float* __restrict__ Wpv, float* __restrict__ Mk) {
    __shared__ __align__(16) float buf[32 * 68 + 32 * 64];  // 16.9 KB
    int g = blockIdx.x, tid = threadIdx.x;
    int t0 = (tid & 15) * 4, t1 = (tid >> 4) * 4;
    float acc[4][4] = {};
    if (g < 64) {
        // ---- Wpv tile: rows i0 (of Wp), cols d0 (of Wv)
        int i0 = (g & 7) * 64, d0 = (g >> 3) * 64;
        float* wp_t = buf;             // [j][i] stride 68 (transposed Wp)
        float* wv_s = buf + 32 * 68;   // [j][d] stride 64
        for (int j0 = 0; j0 < DD; j0 += 32) {
#pragma unroll
            for (int q2 = 0; q2 < 2; ++q2) {
                int s = tid * 2 + q2;          // 0..511
                int i = s >> 3, j4 = (s & 7) * 4;
                float4 v = *reinterpret_cast<const float4*>(
                    Wp + (size_t)(i0 + i) * DD + j0 + j4);
                wp_t[(j4 + 0) * 68 + i] = v.x; wp_t[(j4 + 1) * 68 + i] = v.y;
                wp_t[(j4 + 2) * 68 + i] = v.z; wp_t[(j4 + 3) * 68 + i] = v.w;
            }
#pragma unroll
            for (int q2 = 0; q2 < 2; ++q2) {
                int s = tid * 2 + q2;
                int j = s >> 4, d4 = (s & 15) * 4;
                *reinterpret_cast<float4*>(&wv_s[j * 64 + d4]) =
                    *reinterpret_cast<const float4*>(
                        Wv + (size_t)(j0 + j) * DD + d0 + d4);
            }
            __syncthreads();
#pragma unroll 8
            for (int j = 0; j < 32; ++j) {
                float4 a = *reinterpret_cast<const float4*>(&wp_t[j * 68 + t0]);
                float4 bv = *reinterpret_cast<const float4*>(&wv_s[j * 64 + t1]);
                float a_[4] = {a.x, a.y, a.z, a.w};
                float b_[4] = {bv.x, bv.y, bv.z, bv.w};
#pragma unroll
                for (int e = 0; e < 4; ++e)
#pragma unroll
                    for (int f = 0; f < 4; ++f) acc[e][f] += a_[e] * b_[f];
            }
            __syncthreads();
        }
#pragma unroll
        for (int e = 0; e < 4; ++e)
            *reinterpret_cast<float4*>(&Wpv[(size_t)(i0 + t0 + e) * DD + d0 + t1]) =
                *reinterpret_cast<float4*>(acc[e]);
    } else {
        // ---- Mk tile: Mk[c][i] = sum_j Wk[j][c] * Wq[j][i]  (both row-j)
        int g2 = g - 64;
        int c0 = (g2 & 7) * 64, i0 = (g2 >> 3) * 64;
        float* wk_s = buf;             // [j][c] stride 68 (padded)
        float* wq_s = buf + 32 * 68;   // [j][i] stride 64
        for (int j0 = 0; j0 < DD; j0 += 32) {
#pragma unroll
            for (int q2 = 0; q2 < 2; ++q2) {
                int s = tid * 2 + q2;
                int j = s >> 4, c4 = (s & 15) * 4;
                float4 v = *reinterpret_cast<const float4*>(
                    Wk + (size_t)(j0 + j) * DD + c0 + c4);
                *reinterpret_cast<float4*>(&wk_s[j * 68 + c4]) = v;
            }
#pragma unroll
            for (int q2 = 0; q2 < 2; ++q2) {
                int s = tid * 2 + q2;
                int j = s >> 4, i4 = (s & 15) * 4;
                *reinterpret_cast<float4*>(&wq_s[j * 64 + i4]) =
                    *reinterpret_cast<const float4*>(
                        Wq + (size_t)(j0 + j) * DD + i0 + i4);
            }
            __syncthreads();
#pragma unroll 8
            for (int j = 0; j < 32; ++j) {
                float4 a = *reinterpret_cast<const float4*>(&wk_s[j * 68 + t0]);
                float4 bv = *reinterpret_cast<const float4*>(&wq_s[j * 64 + t1]);
                float a_[4] = {a.x, a.y, a.z, a.w};
                float b_[4] = {bv.x, bv.y, bv.z, bv.w};
#pragma unroll
                for (int e = 0; e < 4; ++e)
#pragma unroll
                    for (int f = 0; f < 4; ++f) acc[e][f] += a_[e] * b_[f];
            }
            __syncthreads();
        }
#pragma unroll
        for (int e = 0; e < 4; ++e)
            *reinterpret_cast<float4*>(&Mk[(size_t)(c0 + t0 + e) * DD + i0 + t1]) =
                *reinterpret_cast<float4*>(acc[e]);
    }
}

// Batched matvec: Y[b][j] = act(W[j][:512] . X[b] + bias[j])
// grid (R/16, B), block 256 (4 waves x 4 rows each).
// mode 0: X = Xa[b] ; mode 1: X = pe[ts[b]] ; mode 2: X = Xa[b] + Xb[b]
__global__ __launch_bounds__(256) void bmv(
    const float* __restrict__ W, int ldw, const float* __restrict__ bias,
    const float* __restrict__ Xa, const float* __restrict__ Xb,
    const int* __restrict__ ts, const float* __restrict__ pe,
    float* __restrict__ Y, int R, int act, int mode) {
    __shared__ __align__(16) float xl[DD];
    int b = blockIdx.y, tid = threadIdx.x, lane = tid & 63, wave = tid >> 6;
    const float* src = (mode == 1) ? (pe + (size_t)ts[b] * DD) : (Xa + (size_t)b * DD);
    if (mode == 2) {
        const float* s2 = Xb + (size_t)b * DD;
        for (int i = tid; i < DD; i += 256) xl[i] = src[i] + s2[i];
    } else {
        for (int i = tid; i < DD; i += 256) xl[i] = src[i];
    }
    __syncthreads();
    float4 xa = reinterpret_cast<const float4*>(xl)[lane * 2];
    float4 xb = reinterpret_cast<const float4*>(xl)[lane * 2 + 1];
    int j0 = blockIdx.x * 16 + wave * 4;
    float s[4];
    wave_dot512x4(W + (size_t)j0 * ldw, ldw, xa, xb, lane, s);
    if (lane < 4) {
        int j = j0 + lane;
        float v = s[lane];
        if (bias) v += bias[j];
        if (act == 1) v = v / (1.f + expf(-v));  // silu
        Y[(size_t)b * R + j] = v;
    }
}

// K2: per (b,n): sim over S (4-row batched loads), argmax, gather best row
// (bf16 only), raw score (free in-register f32 dot with qk during gather).
// Blocks < 1024 also convert Wd1 right half to bf16.
__global__ __launch_bounds__(256) void k2_sim(
    const float* __restrict__ fusion, const float* __restrict__ tif,
    const float* __restrict__ x, const float* __restrict__ qk,
    const float* __restrict__ Wd1, ushort* __restrict__ Wb,
    ushort* __restrict__ abf, float* __restrict__ score) {
    __shared__ __align__(16) float fb[DD];
    __shared__ float bv_s[4];
    __shared__ int bi_s[4];
    __shared__ int bidx_s;
    __shared__ float dred[4];
    int bn = blockIdx.x, b = bn >> 7;
    int tid = threadIdx.x, lane = tid & 63, wave = tid >> 6;

    // convWb prologue: 1024 blocks x 256 thr x 2 elems = 524288 elems
    if (bn < 1024) {
        int idx = (bn * 256 + tid) * 2;
        int r = idx >> 9, k = idx & 511;
        float2 v = *reinterpret_cast<const float2*>(Wd1 + (size_t)r * 1024 + 512 + k);
        ushort2 o = {f2bf(v.x), f2bf(v.y)};
        *reinterpret_cast<ushort2*>(Wb + (size_t)r * 512 + k) = o;
    }

    for (int i = tid; i < DD; i += 256) fb[i] = fusion[(size_t)b * DD + i];
    __syncthreads();
    float4 xa = reinterpret_cast<const float4*>(fb)[lane * 2];
    float4 xb = reinterpret_cast<const float4*>(fb)[lane * 2 + 1];
    const float* base = tif + (size_t)bn * SS * DD;
    float bv = -INFINITY;
    int bi = 0;
    for (int s0 = wave * 16; s0 < wave * 16 + 16; s0 += 4) {
        float sv[4];
        wave_dot512x4(base + (size_t)s0 * DD, DD, xa, xb, lane, sv);
#pragma unroll
        for (int r = 0; r < 4; ++r)
            if (sv[r] > bv) { bv = sv[r]; bi = s0 + r; }  // strict >: first max
    }
    if (lane == 0) { bv_s[wave] = bv; bi_s[wave] = bi; }
    __syncthreads();
    if (tid == 0) {
        float v = bv_s[0]; int i0 = bi_s[0];
        for (int w = 1; w < 4; w++)
            if (bv_s[w] > v) { v = bv_s[w]; i0 = bi_s[w]; }  // waves ascend in s
        bidx_s = i0;
    }
    __syncthreads();
    const float* src = base + (size_t)bidx_s * DD;
    const float* qkb = qk + (size_t)b * DD;
    float local = 0.f;
    for (int i = tid; i < DD; i += 256) {
        float vv = src[i];
        abf[(size_t)bn * DD + i] = f2bf(vv);
        local += vv * qkb[i];
    }
#pragma unroll
    for (int off = 32; off; off >>= 1) local += __shfl_xor(local, off);
    if (lane == 0) dred[wave] = local;
    __syncthreads();
    if (tid == 0) score[bn] = dred[0] + dred[1] + dred[2] + dred[3] + x[bn];
}

// vsum (softmax fused, computed redundantly per block). grid (2, B), block 256.
// Reads the bf16 abf copy.
__global__ __launch_bounds__(256) void k_vsum(
    const float* __restrict__ score, const ushort* __restrict__ abf,
    const float* __restrict__ cond,
    float* __restrict__ wout, float* __restrict__ vsum) {
    __shared__ float wl[NN];
    __shared__ float redm[2], reds[2];
    int b = blockIdx.y, tid = threadIdx.x, lane = tid & 63, wave = tid >> 6;
    float v = 0.f;
    if (tid < NN) {
        v = score[b * NN + tid];
        float m = v;
#pragma unroll
        for (int off = 32; off; off >>= 1) m = fmaxf(m, __shfl_xor(m, off));
        if (lane == 0) redm[wave] = m;
    }
    __syncthreads();
    float m = fmaxf(redm[0], redm[1]);
    if (tid < NN) {
        float e = expf(v - m);
        wl[tid] = e;
        float s = e;
#pragma unroll
        for (int off = 32; off; off >>= 1) s += __shfl_xor(s, off);
        if (lane == 0) reds[wave] = s;
    }
    __syncthreads();
    float inv = 1.f / (reds[0] + reds[1]);
    if (blockIdx.x == 0 && tid < NN) wout[b * NN + tid] = wl[tid] * inv;
    int d = blockIdx.x * 256 + tid;
    const ushort* base = abf + (size_t)b * NN * DD + d;
    float s = 0.f;
#pragma unroll 8
    for (int n = 0; n < NN; n++) s += wl[n] * bf2f(base[(size_t)n * DD]);
    vsum[(size_t)b * DD + d] = s * inv + cond[(size_t)b * DD + d];
}

// K4: bf16 MFMA GEMM C[4096,1024] = Abf[4096,512] x Wb^T, fused u+relu+Wd2.
// Double-buffered LDS; u-prologue overlapped with stage-0 loads.
__global__ __launch_bounds__(256) void k4_mfma(
    const ushort* __restrict__ Abf, const ushort* __restrict__ Wb,
    const float* __restrict__ Wd1, const float* __restrict__ bd1,
    const float* __restrict__ ne, const float* __restrict__ Wd2,
    float* __restrict__ p_part) {
    __shared__ ushort aS[2][128 * 64];  // 2 x 16 KB
    __shared__ ushort bS[2][128 * 64];
    __shared__ __align__(16) float nel[DD];
    __shared__ float uloc[128];
    int tid = threadIdx.x, l = tid & 63, w = tid >> 6;
    int m0 = blockIdx.x * 128, n0 = blockIdx.y * 128;
    int b = blockIdx.x;  // BM=128 == N rows per batch
    int wm = w >> 1, wn = w & 1;

    for (int i = tid; i < DD; i += 256) nel[i] = ne[(size_t)b * DD + i];
    __syncthreads();
    float4 na = reinterpret_cast<const float4*>(nel)[l * 2];
    float4 nb = reinterpret_cast<const float4*>(nel)[l * 2 + 1];

#define STAGE(K0, BUF)                                                         \
    {                                                                          \
        _Pragma("unroll") for (int i = 0; i < 4; ++i) {                        \
            int L = i * 4096 + w * 1024 + l * 16;                              \
            int row = L >> 7;                                                  \
            int bo = L & 127;                                                  \
            int sb = bo ^ ((row & 7) << 4);                                    \
            const ushort* ga = Abf + (size_t)(m0 + row) * DD + (K0) + (sb >> 1); \
            const ushort* gb = Wb + (size_t)(n0 + row) * DD + (K0) + (sb >> 1);  \
            __builtin_amdgcn_global_load_lds(                                  \
                (const __attribute__((address_space(1))) void*)ga,             \
                (__attribute__((address_space(3))) void*)(aS[BUF] + i * 2048 + w * 512), \
                16, 0, 0);                                                     \
            __builtin_amdgcn_global_load_lds(                                  \
                (const __attribute__((address_space(1))) void*)gb,             \
                (__attribute__((address_space(3))) void*)(bS[BUF] + i * 2048 + w * 512), \
                16, 0, 0);                                                     \
        }                                                                      \
    }

    STAGE(0, 0);
    // u-prologue overlaps stage-0: u[r] = Wd1_a[n0+r].ne[b] + bd1[n0+r]
    for (int j0 = 0; j0 < 32; j0 += 4) {
        int r = w * 32 + j0;
        float s[4];
        wave_dot512x4(Wd1 + (size_t)(n0 + r) * 1024, 1024, na, nb, l, s);
        if (l < 4) uloc[r + l] = s[l] + bd1[n0 + r + l];
    }
    __syncthreads();

    f32x4 acc[4][4];
#pragma unroll
    for (int i = 0; i < 4; i++)
#pragma unroll
        for (int j = 0; j < 4; j++) acc[i][j] = (f32x4){0.f, 0.f, 0.f, 0.f};

    int cur = 0;
    for (int k0 = 0; k0 < DD; k0 += 64) {
        if (k0 + 64 < DD) STAGE(k0 + 64, cur ^ 1);  // prefetch into other buf
#pragma unroll
        for (int kk = 0; kk < 2; ++kk) {
            short8 af[4], bf[4];
#pragma unroll
            for (int f = 0; f < 4; ++f) {
                int ra = wm * 64 + f * 16 + (l & 15);
                int boa = (((l >> 4) * 16 + kk * 64)) ^ ((ra & 7) << 4);
                af[f] = *reinterpret_cast<const short8*>(&aS[cur][ra * 64 + (boa >> 1)]);
                int rb = wn * 64 + f * 16 + (l & 15);
                int bob = (((l >> 4) * 16 + kk * 64)) ^ ((rb & 7) << 4);
                bf[f] = *reinterpret_cast<const short8*>(&bS[cur][rb * 64 + (bob >> 1)]);
            }
#pragma unroll
            for (int fm = 0; fm < 4; ++fm)
#pragma unroll
                for (int fn = 0; fn < 4; ++fn)
                    acc[fm][fn] = __builtin_amdgcn_mfma_f32_16x16x32_bf16(
                        af[fm], bf[fn], acc[fm][fn], 0, 0, 0);
        }
        __syncthreads();
        cur ^= 1;
    }
#undef STAGE
#pragma unroll
    for (int fm = 0; fm < 4; ++fm) {
#pragma unroll
        for (int reg = 0; reg < 4; ++reg) {
            float pp = 0.f;
#pragma unroll
            for (int fn = 0; fn < 4; ++fn) {
                int rl = wn * 64 + fn * 16 + (l & 15);
                float hh = acc[fm][fn][reg] + uloc[rl];
                if (hh > 0.f) pp += Wd2[n0 + rl] * hh;
            }
#pragma unroll
            for (int off = 1; off < 16; off <<= 1) pp += __shfl_xor(pp, off);
            if ((l & 15) == 0) {
                int m = m0 + wm * 64 + fm * 16 + (l >> 4) * 4 + reg;
                p_part[(size_t)m * 16 + blockIdx.y * 2 + wn] = pp;
            }
        }
    }
}

// K5: p = sum(p_part) + bd2 + w; bitonic sort 128 descending per b.
__global__ __launch_bounds__(128) void k5_sort(
    const float* __restrict__ p_part, const float* __restrict__ wout,
    const float* __restrict__ bd2, float* __restrict__ out) {
    __shared__ float v[NN];
    int b = blockIdx.x, tid = threadIdx.x;
    int bn = b * NN + tid;
    float s = bd2[0] + wout[bn];
#pragma unroll
    for (int c = 0; c < 16; c++) s += p_part[(size_t)bn * 16 + c];
    v[tid] = s;
    __syncthreads();
    for (int k = 2; k <= NN; k <<= 1) {
        for (int j = k >> 1; j > 0; j >>= 1) {
            int ixj = tid ^ j;
            if (ixj > tid) {
                float a = v[tid], bb2 = v[ixj];
                bool desc = (tid & k) == 0;
                if (desc ? (a < bb2) : (a > bb2)) { v[tid] = bb2; v[ixj] = a; }
            }
            __syncthreads();
        }
    }
    out[bn] = v[tid];
}

extern "C" void kernel_launch(void* const* d_in, const int* in_sizes, int n_in,
                              void* d_out, int out_size, void* d_ws, size_t ws_size,
                              hipStream_t stream) {
    const float* x      = (const float*)d_in[0];
    const int*   ts     = (const int*)d_in[1];
    const float* fusion = (const float*)d_in[2];
    const float* tif    = (const float*)d_in[3];
    const float* pe     = (const float*)d_in[4];
    const float* Wq     = (const float*)d_in[5];
    const float* Wk     = (const float*)d_in[6];
    const float* Wv     = (const float*)d_in[7];
    const float* Wp     = (const float*)d_in[8];
    const float* bp     = (const float*)d_in[9];
    const float* Wt1    = (const float*)d_in[10];
    const float* bt1    = (const float*)d_in[11];
    const float* Wt2    = (const float*)d_in[12];
    const float* bt2    = (const float*)d_in[13];
    const float* Wd1    = (const float*)d_in[14];
    const float* bd1    = (const float*)d_in[15];
    const float* Wd2    = (const float*)d_in[16];
    const float* bd2    = (const float*)d_in[17];

    float* ws = (float*)d_ws;
    float* cond     = ws;                    // 16384
    float* qk       = cond + 16384;          // 16384
    float* h        = qk + 16384;            // 16384
    float* score    = h + 16384;             // 4096
    float* wout     = score + 4096;          // 4096
    float* vsum     = wout + 4096;           // 16384
    float* ne       = vsum + 16384;          // 16384
    float* Mk       = ne + 16384;            // 262144 (1 MB)
    float* Wpv      = Mk + 262144;           // 262144 (1 MB)
    float* p_part   = Wpv + 262144;          // 65536
    ushort* Abf     = (ushort*)(p_part + 65536);  // 2097152 ushorts (4 MB)
    ushort* Wb      = Abf + 2097152;         // 524288 ushorts (1 MB)
    float* out = (float*)d_out;

    // weight precompute: Mk = Wk^T@Wq, Wpv = Wp@Wv (independent, first)
    hipLaunchKernelGGL(k_wprep, dim3(128), dim3(256), 0, stream,
                       Wp, Wv, Wk, Wq, Wpv, Mk);

    // cond chain: h -> cond -> qk (qk = Mk@(fusion+cond), collapsed)
    hipLaunchKernelGGL(bmv, dim3(32, BB), dim3(256), 0, stream,
                       Wt1, DD, bt1, nullptr, nullptr, ts, pe, h, DD, 1, 1);
    hipLaunchKernelGGL(bmv, dim3(32, BB), dim3(256), 0, stream,
                       Wt2, DD, bt2, h, nullptr, nullptr, nullptr, cond, DD, 0, 0);
    hipLaunchKernelGGL(bmv, dim3(32, BB), dim3(256), 0, stream,
                       Mk, DD, nullptr, fusion, cond, nullptr, nullptr, qk, DD, 0, 2);

    // the 537MB streamer (+ convWb prologue, + free in-register score)
    hipLaunchKernelGGL(k2_sim, dim3(BB * NN), dim3(256), 0, stream,
                       fusion, tif, x, qk, Wd1, Wb, Abf, score);

    // attention tail: softmax+vsum, then ne = Wpv@vsum + bp (collapsed)
    hipLaunchKernelGGL(k_vsum, dim3(2, BB), dim3(256), 0, stream,
                       score, Abf, cond, wout, vsum);
    hipLaunchKernelGGL(bmv, dim3(32, BB), dim3(256), 0, stream,
                       Wpv, DD, bp, vsum, nullptr, nullptr, nullptr, ne, DD, 0, 0);

    // decode GEMM (MFMA, dbuf, u folded) + sort
    hipLaunchKernelGGL(k4_mfma, dim3(32, 8), dim3(256), 0, stream,
                       Abf, Wb, Wd1, bd1, ne, Wd2, p_part);
    hipLaunchKernelGGL(k5_sort, dim3(BB), dim3(128), 0, stream,
                       p_part, wout, bd2, out);
}

// Round 15
// 181.115 us; speedup vs baseline: 1.1020x; 1.1020x over previous
//
#include <hip/hip_runtime.h>
#include <hip/hip_bf16.h>
#include <math.h>

// Problem: B=32, N=128, S=64, D=512
// Output: [B,N] f32, each row sorted descending.
// Round 15: exact revert to r13 (verified best, 181.9us).
// Failed alternatives (all measured): r4/r5/r11 device barriers (8-45us each),
// r7 intra-block chain, r8/r9 flag helpers, r12 co-compiled Wpv (VGPR cliff),
// r14 weight-precompute k_wprep (+18us). The 10-launch pipeline with k2 at
// the HBM roofline is this decomposition's floor.

#define BB 32
#define NN 128
#define SS 64
#define DD 512

typedef __attribute__((ext_vector_type(8))) short short8;
typedef __attribute__((ext_vector_type(4))) float f32x4;

__device__ __forceinline__ ushort f2bf(float f) {
    unsigned u = __float_as_uint(f);
    unsigned r = (u + 0x7fffu + ((u >> 16) & 1u)) >> 16;
    return (ushort)r;
}
__device__ __forceinline__ float bf2f(ushort u) {
    return __uint_as_float(((unsigned)u) << 16);
}

// Batched wave-dot: 4 rows of W (stride ldw) dotted with x (in regs xa/xb).
// All 8 row-loads issued before the serial shuffle reduces.
__device__ __forceinline__ void wave_dot512x4(
    const float* __restrict__ w, size_t ldw, float4 xa, float4 xb,
    int lane, float out[4]) {
    float4 ra[4], rb[4];
#pragma unroll
    for (int r = 0; r < 4; ++r) {
        const float4* row = reinterpret_cast<const float4*>(w + (size_t)r * ldw);
        ra[r] = row[lane * 2];
        rb[r] = row[lane * 2 + 1];
    }
#pragma unroll
    for (int r = 0; r < 4; ++r) {
        float s = ra[r].x * xa.x + ra[r].y * xa.y + ra[r].z * xa.z + ra[r].w * xa.w
                + rb[r].x * xb.x + rb[r].y * xb.y + rb[r].z * xb.z + rb[r].w * xb.w;
#pragma unroll
        for (int off = 32; off; off >>= 1) s += __shfl_xor(s, off);
        out[r] = s;
    }
}

// Batched matvec: Y[b][j] = act(W[j][:512] . X[b] + bias[j])
// grid (R/16, B), block 256 (4 waves x 4 rows each).
// mode 0: X = Xa[b] ; mode 1: X = pe[ts[b]] ; mode 2: X = Xa[b] + Xb[b]
__global__ __launch_bounds__(256) void bmv(
    const float* __restrict__ W, int ldw, const float* __restrict__ bias,
    const float* __restrict__ Xa, const float* __restrict__ Xb,
    const int* __restrict__ ts, const float* __restrict__ pe,
    float* __restrict__ Y, int R, int act, int mode) {
    __shared__ __align__(16) float xl[DD];
    int b = blockIdx.y, tid = threadIdx.x, lane = tid & 63, wave = tid >> 6;
    const float* src = (mode == 1) ? (pe + (size_t)ts[b] * DD) : (Xa + (size_t)b * DD);
    if (mode == 2) {
        const float* s2 = Xb + (size_t)b * DD;
        for (int i = tid; i < DD; i += 256) xl[i] = src[i] + s2[i];
    } else {
        for (int i = tid; i < DD; i += 256) xl[i] = src[i];
    }
    __syncthreads();
    float4 xa = reinterpret_cast<const float4*>(xl)[lane * 2];
    float4 xb = reinterpret_cast<const float4*>(xl)[lane * 2 + 1];
    int j0 = blockIdx.x * 16 + wave * 4;
    float s[4];
    wave_dot512x4(W + (size_t)j0 * ldw, ldw, xa, xb, lane, s);
    if (lane < 4) {
        int j = j0 + lane;
        float v = s[lane];
        if (bias) v += bias[j];
        if (act == 1) v = v / (1.f + expf(-v));  // silu
        Y[(size_t)b * R + j] = v;
    }
}

// qk[b][c] = sum_j q[b][j] * Wk[j][c]   (transposed matvec)
__global__ __launch_bounds__(256) void k_qk(
    const float* __restrict__ Wk, const float* __restrict__ q,
    float* __restrict__ qk) {
    __shared__ __align__(16) float ql[DD];
    __shared__ float part[4][64];
    int b = blockIdx.y, c0 = blockIdx.x * 64;
    int tid = threadIdx.x, lane = tid & 63, wave = tid >> 6;
    for (int i = tid; i < DD; i += 256) ql[i] = q[(size_t)b * DD + i];
    __syncthreads();
    float p = 0.f;
    for (int j = wave * 128; j < wave * 128 + 128; ++j)
        p += ql[j] * Wk[(size_t)j * DD + c0 + lane];
    part[wave][lane] = p;
    __syncthreads();
    if (tid < 64)
        qk[(size_t)b * DD + c0 + tid] =
            part[0][tid] + part[1][tid] + part[2][tid] + part[3][tid];
}

// K2: per (b,n): sim over S (4-row batched loads), argmax, gather best row
// (bf16 only), raw score (free in-register f32 dot with qk during gather).
// Blocks < 1024 also convert Wd1 right half to bf16.
__global__ __launch_bounds__(256) void k2_sim(
    const float* __restrict__ fusion, const float* __restrict__ tif,
    const float* __restrict__ x, const float* __restrict__ qk,
    const float* __restrict__ Wd1, ushort* __restrict__ Wb,
    ushort* __restrict__ abf, float* __restrict__ score) {
    __shared__ __align__(16) float fb[DD];
    __shared__ float bv_s[4];
    __shared__ int bi_s[4];
    __shared__ int bidx_s;
    __shared__ float dred[4];
    int bn = blockIdx.x, b = bn >> 7;
    int tid = threadIdx.x, lane = tid & 63, wave = tid >> 6;

    // convWb prologue: 1024 blocks x 256 thr x 2 elems = 524288 elems
    if (bn < 1024) {
        int idx = (bn * 256 + tid) * 2;
        int r = idx >> 9, k = idx & 511;
        float2 v = *reinterpret_cast<const float2*>(Wd1 + (size_t)r * 1024 + 512 + k);
        ushort2 o = {f2bf(v.x), f2bf(v.y)};
        *reinterpret_cast<ushort2*>(Wb + (size_t)r * 512 + k) = o;
    }

    for (int i = tid; i < DD; i += 256) fb[i] = fusion[(size_t)b * DD + i];
    __syncthreads();
    float4 xa = reinterpret_cast<const float4*>(fb)[lane * 2];
    float4 xb = reinterpret_cast<const float4*>(fb)[lane * 2 + 1];
    const float* base = tif + (size_t)bn * SS * DD;
    float bv = -INFINITY;
    int bi = 0;
    for (int s0 = wave * 16; s0 < wave * 16 + 16; s0 += 4) {
        float sv[4];
        wave_dot512x4(base + (size_t)s0 * DD, DD, xa, xb, lane, sv);
#pragma unroll
        for (int r = 0; r < 4; ++r)
            if (sv[r] > bv) { bv = sv[r]; bi = s0 + r; }  // strict >: first max
    }
    if (lane == 0) { bv_s[wave] = bv; bi_s[wave] = bi; }
    __syncthreads();
    if (tid == 0) {
        float v = bv_s[0]; int i0 = bi_s[0];
        for (int w = 1; w < 4; w++)
            if (bv_s[w] > v) { v = bv_s[w]; i0 = bi_s[w]; }  // waves ascend in s
        bidx_s = i0;
    }
    __syncthreads();
    const float* src = base + (size_t)bidx_s * DD;
    const float* qkb = qk + (size_t)b * DD;
    float local = 0.f;
    for (int i = tid; i < DD; i += 256) {
        float vv = src[i];
        abf[(size_t)bn * DD + i] = f2bf(vv);
        local += vv * qkb[i];
    }
#pragma unroll
    for (int off = 32; off; off >>= 1) local += __shfl_xor(local, off);
    if (lane == 0) dred[wave] = local;
    __syncthreads();
    if (tid == 0) score[bn] = dred[0] + dred[1] + dred[2] + dred[3] + x[bn];
}

// vsum (softmax fused, computed redundantly per block). grid (2, B), block 256.
// Reads the bf16 abf copy (f32 tif_best dropped — halves this kernel's reads).
__global__ __launch_bounds__(256) void k_vsum(
    const float* __restrict__ score, const ushort* __restrict__ abf,
    const float* __restrict__ cond,
    float* __restrict__ wout, float* __restrict__ vsum) {
    __shared__ float wl[NN];
    __shared__ float redm[2], reds[2];
    int b = blockIdx.y, tid = threadIdx.x, lane = tid & 63, wave = tid >> 6;
    float v = 0.f;
    if (tid < NN) {
        v = score[b * NN + tid];
        float m = v;
#pragma unroll
        for (int off = 32; off; off >>= 1) m = fmaxf(m, __shfl_xor(m, off));
        if (lane == 0) redm[wave] = m;
    }
    __syncthreads();
    float m = fmaxf(redm[0], redm[1]);
    if (tid < NN) {
        float e = expf(v - m);
        wl[tid] = e;
        float s = e;
#pragma unroll
        for (int off = 32; off; off >>= 1) s += __shfl_xor(s, off);
        if (lane == 0) reds[wave] = s;
    }
    __syncthreads();
    float inv = 1.f / (reds[0] + reds[1]);
    if (blockIdx.x == 0 && tid < NN) wout[b * NN + tid] = wl[tid] * inv;
    int d = blockIdx.x * 256 + tid;
    const ushort* base = abf + (size_t)b * NN * DD + d;
    float s = 0.f;
#pragma unroll 8
    for (int n = 0; n < NN; n++) s += wl[n] * bf2f(base[(size_t)n * DD]);
    vsum[(size_t)b * DD + d] = s * inv + cond[(size_t)b * DD + d];
}

// K4: bf16 MFMA GEMM C[4096,1024] = Abf[4096,512] x Wb^T, fused u+relu+Wd2.
// Double-buffered LDS; u-prologue overlapped with stage-0 loads.
__global__ __launch_bounds__(256) void k4_mfma(
    const ushort* __restrict__ Abf, const ushort* __restrict__ Wb,
    const float* __restrict__ Wd1, const float* __restrict__ bd1,
    const float* __restrict__ ne, const float* __restrict__ Wd2,
    float* __restrict__ p_part) {
    __shared__ ushort aS[2][128 * 64];  // 2 x 16 KB
    __shared__ ushort bS[2][128 * 64];
    __shared__ __align__(16) float nel[DD];
    __shared__ float uloc[128];
    int tid = threadIdx.x, l = tid & 63, w = tid >> 6;
    int m0 = blockIdx.x * 128, n0 = blockIdx.y * 128;
    int b = blockIdx.x;  // BM=128 == N rows per batch
    int wm = w >> 1, wn = w & 1;

    for (int i = tid; i < DD; i += 256) nel[i] = ne[(size_t)b * DD + i];
    __syncthreads();
    float4 na = reinterpret_cast<const float4*>(nel)[l * 2];
    float4 nb = reinterpret_cast<const float4*>(nel)[l * 2 + 1];

#define STAGE(K0, BUF)                                                         \
    {                                                                          \
        _Pragma("unroll") for (int i = 0; i < 4; ++i) {                        \
            int L = i * 4096 + w * 1024 + l * 16;                              \
            int row = L >> 7;                                                  \
            int bo = L & 127;                                                  \
            int sb = bo ^ ((row & 7) << 4);                                    \
            const ushort* ga = Abf + (size_t)(m0 + row) * DD + (K0) + (sb >> 1); \
            const ushort* gb = Wb + (size_t)(n0 + row) * DD + (K0) + (sb >> 1);  \
            __builtin_amdgcn_global_load_lds(                                  \
                (const __attribute__((address_space(1))) void*)ga,             \
                (__attribute__((address_space(3))) void*)(aS[BUF] + i * 2048 + w * 512), \
                16, 0, 0);                                                     \
            __builtin_amdgcn_global_load_lds(                                  \
                (const __attribute__((address_space(1))) void*)gb,             \
                (__attribute__((address_space(3))) void*)(bS[BUF] + i * 2048 + w * 512), \
                16, 0, 0);                                                     \
        }                                                                      \
    }

    STAGE(0, 0);
    // u-prologue overlaps stage-0: u[r] = Wd1_a[n0+r].ne[b] + bd1[n0+r]
    for (int j0 = 0; j0 < 32; j0 += 4) {
        int r = w * 32 + j0;
        float s[4];
        wave_dot512x4(Wd1 + (size_t)(n0 + r) * 1024, 1024, na, nb, l, s);
        if (l < 4) uloc[r + l] = s[l] + bd1[n0 + r + l];
    }
    __syncthreads();

    f32x4 acc[4][4];
#pragma unroll
    for (int i = 0; i < 4; i++)
#pragma unroll
        for (int j = 0; j < 4; j++) acc[i][j] = (f32x4){0.f, 0.f, 0.f, 0.f};

    int cur = 0;
    for (int k0 = 0; k0 < DD; k0 += 64) {
        if (k0 + 64 < DD) STAGE(k0 + 64, cur ^ 1);  // prefetch into other buf
#pragma unroll
        for (int kk = 0; kk < 2; ++kk) {
            short8 af[4], bf[4];
#pragma unroll
            for (int f = 0; f < 4; ++f) {
                int ra = wm * 64 + f * 16 + (l & 15);
                int boa = (((l >> 4) * 16 + kk * 64)) ^ ((ra & 7) << 4);
                af[f] = *reinterpret_cast<const short8*>(&aS[cur][ra * 64 + (boa >> 1)]);
                int rb = wn * 64 + f * 16 + (l & 15);
                int bob = (((l >> 4) * 16 + kk * 64)) ^ ((rb & 7) << 4);
                bf[f] = *reinterpret_cast<const short8*>(&bS[cur][rb * 64 + (bob >> 1)]);
            }
#pragma unroll
            for (int fm = 0; fm < 4; ++fm)
#pragma unroll
                for (int fn = 0; fn < 4; ++fn)
                    acc[fm][fn] = __builtin_amdgcn_mfma_f32_16x16x32_bf16(
                        af[fm], bf[fn], acc[fm][fn], 0, 0, 0);
        }
        __syncthreads();
        cur ^= 1;
    }
#undef STAGE
#pragma unroll
    for (int fm = 0; fm < 4; ++fm) {
#pragma unroll
        for (int reg = 0; reg < 4; ++reg) {
            float pp = 0.f;
#pragma unroll
            for (int fn = 0; fn < 4; ++fn) {
                int rl = wn * 64 + fn * 16 + (l & 15);
                float hh = acc[fm][fn][reg] + uloc[rl];
                if (hh > 0.f) pp += Wd2[n0 + rl] * hh;
            }
#pragma unroll
            for (int off = 1; off < 16; off <<= 1) pp += __shfl_xor(pp, off);
            if ((l & 15) == 0) {
                int m = m0 + wm * 64 + fm * 16 + (l >> 4) * 4 + reg;
                p_part[(size_t)m * 16 + blockIdx.y * 2 + wn] = pp;
            }
        }
    }
}

// K5: p = sum(p_part) + bd2 + w; bitonic sort 128 descending per b.
__global__ __launch_bounds__(128) void k5_sort(
    const float* __restrict__ p_part, const float* __restrict__ wout,
    const float* __restrict__ bd2, float* __restrict__ out) {
    __shared__ float v[NN];
    int b = blockIdx.x, tid = threadIdx.x;
    int bn = b * NN + tid;
    float s = bd2[0] + wout[bn];
#pragma unroll
    for (int c = 0; c < 16; c++) s += p_part[(size_t)bn * 16 + c];
    v[tid] = s;
    __syncthreads();
    for (int k = 2; k <= NN; k <<= 1) {
        for (int j = k >> 1; j > 0; j >>= 1) {
            int ixj = tid ^ j;
            if (ixj > tid) {
                float a = v[tid], bb2 = v[ixj];
                bool desc = (tid & k) == 0;
                if (desc ? (a < bb2) : (a > bb2)) { v[tid] = bb2; v[ixj] = a; }
            }
            __syncthreads();
        }
    }
    out[bn] = v[tid];
}

extern "C" void kernel_launch(void* const* d_in, const int* in_sizes, int n_in,
                              void* d_out, int out_size, void* d_ws, size_t ws_size,
                              hipStream_t stream) {
    const float* x      = (const float*)d_in[0];
    const int*   ts     = (const int*)d_in[1];
    const float* fusion = (const float*)d_in[2];
    const float* tif    = (const float*)d_in[3];
    const float* pe     = (const float*)d_in[4];
    const float* Wq     = (const float*)d_in[5];
    const float* Wk     = (const float*)d_in[6];
    const float* Wv     = (const float*)d_in[7];
    const float* Wp     = (const float*)d_in[8];
    const float* bp     = (const float*)d_in[9];
    const float* Wt1    = (const float*)d_in[10];
    const float* bt1    = (const float*)d_in[11];
    const float* Wt2    = (const float*)d_in[12];
    const float* bt2    = (const float*)d_in[13];
    const float* Wd1    = (const float*)d_in[14];
    const float* bd1    = (const float*)d_in[15];
    const float* Wd2    = (const float*)d_in[16];
    const float* bd2    = (const float*)d_in[17];

    float* ws = (float*)d_ws;
    float* cond     = ws;                    // 16384
    float* qk       = cond + 16384;          // 16384
    float* h        = qk + 16384;            // 16384
    float* q        = h + 16384;             // 16384
    float* score    = q + 16384;             // 4096
    float* wout     = score + 4096;          // 4096
    float* vsum     = wout + 4096;           // 16384
    float* ve       = vsum + 16384;          // 16384
    float* ne       = ve + 16384;            // 16384
    float* p_part   = ne + 16384;            // 65536
    ushort* Abf     = (ushort*)(p_part + 65536);  // 2097152 ushorts (4 MB)
    ushort* Wb      = Abf + 2097152;         // 524288 ushorts (1 MB)
    float* out = (float*)d_out;

    // cond chain (grid-parallel over rows x batch)
    hipLaunchKernelGGL(bmv, dim3(32, BB), dim3(256), 0, stream,
                       Wt1, DD, bt1, nullptr, nullptr, ts, pe, h, DD, 1, 1);
    hipLaunchKernelGGL(bmv, dim3(32, BB), dim3(256), 0, stream,
                       Wt2, DD, bt2, h, nullptr, nullptr, nullptr, cond, DD, 0, 0);
    hipLaunchKernelGGL(bmv, dim3(32, BB), dim3(256), 0, stream,
                       Wq, DD, nullptr, fusion, cond, nullptr, nullptr, q, DD, 0, 2);
    hipLaunchKernelGGL(k_qk, dim3(8, BB), dim3(256), 0, stream, Wk, q, qk);

    // the 537MB streamer (+ convWb prologue, + free in-register score)
    hipLaunchKernelGGL(k2_sim, dim3(BB * NN), dim3(256), 0, stream,
                       fusion, tif, x, qk, Wd1, Wb, Abf, score);

    // attention chain (k_vsum reads bf16 abf)
    hipLaunchKernelGGL(k_vsum, dim3(2, BB), dim3(256), 0, stream,
                       score, Abf, cond, wout, vsum);
    hipLaunchKernelGGL(bmv, dim3(32, BB), dim3(256), 0, stream,
                       Wv, DD, nullptr, vsum, nullptr, nullptr, nullptr, ve, DD, 0, 0);
    hipLaunchKernelGGL(bmv, dim3(32, BB), dim3(256), 0, stream,
                       Wp, DD, bp, ve, nullptr, nullptr, nullptr, ne, DD, 0, 0);

    // decode GEMM (MFMA, dbuf, u folded) + sort
    hipLaunchKernelGGL(k4_mfma, dim3(32, 8), dim3(256), 0, stream,
                       Abf, Wb, Wd1, bd1, ne, Wd2, p_part);
    hipLaunchKernelGGL(k5_sort, dim3(BB), dim3(128), 0, stream,
                       p_part, wout, bd2, out);
}